// Round 8
// baseline (330.156 us; speedup 1.0000x reference)
//
#include <hip/hip_runtime.h>
#include <hip/hip_bf16.h>
#include <hip/hip_cooperative_groups.h>
namespace cg = cooperative_groups;

#define N_NODES    100000
#define N_EDGES    1600000
#define NODE_DIM   128
#define EDGE_DIM   32
#define GLOBAL_DIM 64
#define HIDDEN_DIM 256
#define N_GRAPHS   512
#define IN_DIM     224   // 128 + 32 + 64
#define ROW33      33    // 32 dims + count col; stride-33 spreads LDS banks

#define NBLK       256                       // 1 block/CU; coop grid must be co-resident
#define NTHR       1024
#define TOTTHR     (NBLK * NTHR)             // 262144
#define EDGE_CH    (N_EDGES / NBLK)          // 6250
#define NSLOT      16                        // global accumulator copies
#define SLOTSZ     (N_GRAPHS * ROW33)        // 16896 ints per slot

// fixed-point scale for int32 accumulation (fp32 atomicAdd = CAS loop on HIP
// without -munsafe-fp-atomics — round-3/4 lesson: int atomics are native).
// int adds are exact & order-independent -> deterministic across replays.
#define FXS   1048576.0f          // 2^20
#define FXINV (1.0f / 1048576.0f)

// ---------------- workspace layout (4-byte units) ----------------
#define WS_NSTART 0                                  // int[513] (pad 1024)
#define WS_NSUM   (WS_NSTART + 1024)                 // float[512*128]
#define WS_ESLOT  (WS_NSUM + N_GRAPHS * NODE_DIM)    // int[16*16896]
#define WS_SEG    (WS_ESLOT + NSLOT * SLOTSZ)        // ushort[1.6M]

__global__ __launch_bounds__(NTHR) void fused(
    const float* __restrict__ x, const int* __restrict__ eidx,
    const float* __restrict__ eattr, const float* __restrict__ u,
    const int* __restrict__ batch,
    const float* __restrict__ W1, const float* __restrict__ b1,
    const float* __restrict__ W2, const float* __restrict__ b2,
    const float* __restrict__ W3, const float* __restrict__ b3,
    float* __restrict__ out,
    int* __restrict__ nstart, float* __restrict__ nsum,
    int* __restrict__ eslot, unsigned short* __restrict__ seg)
{
    __shared__ int ssum[SLOTSZ];             // 67.6 KB, reused by all phases
    cg::grid_group grid = cg::this_grid();
    const int t = threadIdx.x;
    const int blk = blockIdx.x;
    const int gtid = blk * NTHR + t;

    // ================= Phase A: seg gather + boundaries + zero =============
    for (int i = gtid; i < N_EDGES / 4; i += TOTTHR) {
        const int4 e4 = reinterpret_cast<const int4*>(eidx)[i];
        ushort4 sv;
        sv.x = (unsigned short)batch[e4.x];
        sv.y = (unsigned short)batch[e4.y];
        sv.z = (unsigned short)batch[e4.z];
        sv.w = (unsigned short)batch[e4.w];
        reinterpret_cast<ushort4*>(seg)[i] = sv;
    }
    if (gtid < N_NODES) {
        const int b0 = batch[gtid];
        if (gtid == 0)
            for (int g = 0; g <= b0; ++g) nstart[g] = 0;
        if (gtid < N_NODES - 1) {
            const int b1v = batch[gtid + 1];
            for (int g = b0 + 1; g <= b1v; ++g) nstart[g] = gtid + 1;
        } else {
            for (int g = b0 + 1; g <= N_GRAPHS; ++g) nstart[g] = N_NODES;
        }
    }
    if (gtid < NSLOT * SLOTSZ / 4)
        reinterpret_cast<int4*>(eslot)[gtid] = int4{0, 0, 0, 0};

    __threadfence();
    grid.sync();

    // ================= Phase B1: edge LDS histogram + 16-slot flush ========
    for (int i = t; i < SLOTSZ; i += NTHR) ssum[i] = 0;
    __syncthreads();

    {
        const int p = t & 7;                 // 8 lanes per 32-float edge row
        const int e1 = blk * EDGE_CH + EDGE_CH;
#pragma unroll 4
        for (int e = blk * EDGE_CH + (t >> 3); e < e1; e += 128) {
            const int s = seg[e];
            const float4 v = *reinterpret_cast<const float4*>(eattr + (size_t)e * EDGE_DIM + p * 4);
            const int b = s * ROW33 + p * 4;
            atomicAdd(&ssum[b + 0], __float2int_rn(v.x * FXS));
            atomicAdd(&ssum[b + 1], __float2int_rn(v.y * FXS));
            atomicAdd(&ssum[b + 2], __float2int_rn(v.z * FXS));
            atomicAdd(&ssum[b + 3], __float2int_rn(v.w * FXS));
            if (p == 0) atomicAdd(&ssum[s * ROW33 + 32], 1);
        }
    }
    __syncthreads();
    {
        int* gs = eslot + (size_t)(blk & (NSLOT - 1)) * SLOTSZ;
        for (int i = t; i < SLOTSZ; i += NTHR) {
            const int v = ssum[i];
            if (v) atomicAdd(gs + i, v);
        }
    }
    __syncthreads();                         // flush reads done before LDS reuse

    // ================= Phase B2: node range-sums (2 graphs per block) ======
    for (int gi = 0; gi < 2; ++gi) {
        const int g = blk * 2 + gi;
        const int dp = t & 63;               // float2 dim-pair
        const int off = t >> 6;              // row offset 0..15
        const int s0 = nstart[g], e0 = nstart[g + 1];

        float ax0 = 0.f, ay0 = 0.f, ax1 = 0.f, ay1 = 0.f;
        float ax2 = 0.f, ay2 = 0.f, ax3 = 0.f, ay3 = 0.f;
        int r = s0 + off;
        for (; r + 48 < e0; r += 64) {
            const float2 v0 = *reinterpret_cast<const float2*>(x + (size_t)(r     ) * NODE_DIM + dp * 2);
            const float2 v1 = *reinterpret_cast<const float2*>(x + (size_t)(r + 16) * NODE_DIM + dp * 2);
            const float2 v2 = *reinterpret_cast<const float2*>(x + (size_t)(r + 32) * NODE_DIM + dp * 2);
            const float2 v3 = *reinterpret_cast<const float2*>(x + (size_t)(r + 48) * NODE_DIM + dp * 2);
            ax0 += v0.x; ay0 += v0.y; ax1 += v1.x; ay1 += v1.y;
            ax2 += v2.x; ay2 += v2.y; ax3 += v3.x; ay3 += v3.y;
        }
        for (; r < e0; r += 16) {
            const float2 v = *reinterpret_cast<const float2*>(x + (size_t)r * NODE_DIM + dp * 2);
            ax0 += v.x; ay0 += v.y;
        }

        float2* part2 = reinterpret_cast<float2*>(ssum);
        __syncthreads();                     // prior LDS readers done
        part2[t] = float2{(ax0 + ax1) + (ax2 + ax3), (ay0 + ay1) + (ay2 + ay3)};
        __syncthreads();
        if (t < 64) {
            float sx = 0.f, sy = 0.f;
#pragma unroll 16
            for (int k = 0; k < 16; ++k) {
                const float2 v = part2[t + 64 * k];
                sx += v.x; sy += v.y;
            }
            reinterpret_cast<float2*>(nsum)[(size_t)g * 64 + t] = float2{sx, sy};
        }
    }

    __threadfence();
    grid.sync();

    // ================= Phase C: finalize + MLP (blocks 0..127, 4 graphs) ===
    if (blk >= N_GRAPHS / 4) return;
    {
        const int gl = t >> 8;               // graph-local 0..3
        const int c  = t & 255;              // column 0..255
        const int g  = blk * 4 + gl;

        int*   sE = ssum;                    // [4][33] edge sums + count
        float* fs = reinterpret_cast<float*>(&ssum[144]);  // [4][224]
        float* hh = fs + 4 * IN_DIM;         // [4][256]
        float* h2 = hh + 4 * HIDDEN_DIM;     // [4][256]
        float* rd = h2 + 4 * HIDDEN_DIM;     // [4][256]

        if (c < 33) {                        // reduce 16 slots
            int s = 0;
#pragma unroll 16
            for (int sl = 0; sl < NSLOT; ++sl)
                s += eslot[(size_t)sl * SLOTSZ + (size_t)g * ROW33 + c];
            sE[gl * 33 + c] = s;
        }
        __syncthreads();

        if (c < NODE_DIM) {
            const float cnt = fmaxf((float)(nstart[g + 1] - nstart[g]), 1.f);
            fs[gl * IN_DIM + c] = nsum[(size_t)g * NODE_DIM + c] / cnt;
        } else if (c < NODE_DIM + EDGE_DIM) {
            const int d = c - NODE_DIM;
            const float ec = fmaxf((float)sE[gl * 33 + 32], 1.f);
            fs[gl * IN_DIM + c] = ((float)sE[gl * 33 + d] * FXINV) / ec;
        } else if (c < IN_DIM) {
            fs[gl * IN_DIM + c] = u[(size_t)g * GLOBAL_DIM + (c - NODE_DIM - EDGE_DIM)];
        }
        __syncthreads();

        // ---- MLP (4 column-groups share the weight streams) ----
        float acc = b1[c];
        const float* fsg = fs + gl * IN_DIM;
        for (int k = 0; k < IN_DIM; ++k) acc = fmaf(fsg[k], W1[k * HIDDEN_DIM + c], acc);
        hh[gl * HIDDEN_DIM + c] = fmaxf(acc, 0.f);
        __syncthreads();

        acc = b2[c];
        const float* hg = hh + gl * HIDDEN_DIM;
        for (int k = 0; k < HIDDEN_DIM; ++k) acc = fmaf(hg[k], W2[k * HIDDEN_DIM + c], acc);
        h2[gl * HIDDEN_DIM + c] = fmaxf(acc, 0.f);
        __syncthreads();

        const int col = c & 63, q = c >> 6;
        acc = 0.f;
        const float* h2g = h2 + gl * HIDDEN_DIM;
        for (int k = q * 64; k < q * 64 + 64; ++k) acc = fmaf(h2g[k], W3[k * GLOBAL_DIM + col], acc);
        rd[gl * 256 + c] = acc;
        __syncthreads();
        if (c < GLOBAL_DIM) {
            out[(size_t)g * GLOBAL_DIM + c] = rd[gl * 256 + c] + rd[gl * 256 + c + 64] +
                                              rd[gl * 256 + c + 128] + rd[gl * 256 + c + 192] + b3[c];
        }
    }
}

extern "C" void kernel_launch(void* const* d_in, const int* in_sizes, int n_in,
                              void* d_out, int out_size, void* d_ws, size_t ws_size,
                              hipStream_t stream) {
    const float* x         = (const float*)d_in[0];
    const int*   edge_idx  = (const int*)d_in[1];    // [2, E]; first E = sources
    const float* edge_attr = (const float*)d_in[2];
    const float* u         = (const float*)d_in[3];
    const int*   batch     = (const int*)d_in[4];
    const float* W1 = (const float*)d_in[5];
    const float* b1 = (const float*)d_in[6];
    const float* W2 = (const float*)d_in[7];
    const float* b2 = (const float*)d_in[8];
    const float* W3 = (const float*)d_in[9];
    const float* b3 = (const float*)d_in[10];
    float* out = (float*)d_out;

    int* ws32 = (int*)d_ws;
    int*            nstart = ws32 + WS_NSTART;
    float*          nsum   = (float*)(ws32 + WS_NSUM);
    int*            eslot  = ws32 + WS_ESLOT;
    unsigned short* seg    = (unsigned short*)(ws32 + WS_SEG);

    void* args[] = {
        (void*)&x, (void*)&edge_idx, (void*)&edge_attr, (void*)&u, (void*)&batch,
        (void*)&W1, (void*)&b1, (void*)&W2, (void*)&b2, (void*)&W3, (void*)&b3,
        (void*)&out, (void*)&nstart, (void*)&nsum, (void*)&eslot, (void*)&seg
    };
    hipLaunchCooperativeKernel((const void*)fused, dim3(NBLK), dim3(NTHR),
                               args, 0, stream);
}

// Round 9
// 90.921 us; speedup vs baseline: 3.6312x; 3.6312x over previous
//
#include <hip/hip_runtime.h>
#include <hip/hip_bf16.h>

#define N_NODES    100000
#define N_EDGES    1600000
#define NODE_DIM   128
#define EDGE_DIM   32
#define GLOBAL_DIM 64
#define HIDDEN_DIM 256
#define N_GRAPHS   512
#define IN_DIM     224   // 128 + 32 + 64
#define ROW33      33    // 32 dims + count col; stride-33 spreads LDS banks

#define EDGE_BLKS  256                       // edge histogram blocks (1024 thr)
#define EDGE_CH    (N_EDGES / EDGE_BLKS)     // 6250
#define SLOTSZ     (N_GRAPHS * ROW33)        // 16896 ints per private slot
#define GPB        2                         // graphs per finalize+MLP block

// fixed-point scale for int32 LDS accumulation (fp32 atomicAdd = CAS loop on
// HIP without -munsafe-fp-atomics — round-3/4 lesson: int atomics are native)
#define FXS   1048576.0f          // 2^20
#define FXINV (1.0f / 1048576.0f)

// ---------------- workspace layout (4-byte units); NOTHING zero-initialized ----
#define WS_NSUM   0                                  // float[512*128]
#define WS_NCNT   (WS_NSUM + N_GRAPHS * NODE_DIM)    // float[512]
#define WS_ESLOT  (WS_NCNT + N_GRAPHS)               // int[256*16896] = 17.3 MB

// ---------------- bulk: edge hist (blocks 0..255) + node sums (256..767) ----
__global__ __launch_bounds__(1024) void bulk(const float* __restrict__ eattr,
                                             const int* __restrict__ eidx,
                                             const float* __restrict__ x,
                                             const int* __restrict__ batch,
                                             int* __restrict__ eslot,
                                             float* __restrict__ nsum,
                                             float* __restrict__ ncnt) {
    __shared__ int ssum[SLOTSZ];             // 67.6 KB (node path reuses 8 KB)
    const int t = threadIdx.x;

    if (blockIdx.x < EDGE_BLKS) {
        // ----- edge scatter-sum: direct gather + 1-deep software prefetch -----
        for (int i = t; i < SLOTSZ; i += 1024) ssum[i] = 0;
        __syncthreads();

        const float4* eattr4 = reinterpret_cast<const float4*>(eattr);
        const int p = t & 7;                 // 8 lanes per 32-float edge row
        const int e1 = blockIdx.x * EDGE_CH + EDGE_CH;
        int e = blockIdx.x * EDGE_CH + (t >> 3);

        // prefetch iteration 0
        int    s_nxt = (e < e1) ? batch[eidx[e]] : 0;
        float4 v_nxt = (e < e1) ? eattr4[(size_t)e * 8 + p] : float4{0.f, 0.f, 0.f, 0.f};

#pragma unroll 2
        for (; e < e1; e += 128) {
            const int s = s_nxt;
            const float4 v = v_nxt;
            const int en = e + 128;
            if (en < e1) {                   // issue next loads before atomics
                s_nxt = batch[eidx[en]];
                v_nxt = eattr4[(size_t)en * 8 + p];
            }
            const int b = s * ROW33 + p * 4;
            atomicAdd(&ssum[b + 0], __float2int_rn(v.x * FXS));
            atomicAdd(&ssum[b + 1], __float2int_rn(v.y * FXS));
            atomicAdd(&ssum[b + 2], __float2int_rn(v.z * FXS));
            atomicAdd(&ssum[b + 3], __float2int_rn(v.w * FXS));
            if (p == 0) atomicAdd(&ssum[s * ROW33 + 32], 1);
        }
        __syncthreads();

        // flush: plain coalesced stores to block-private slot (no zero, no atomics)
        int* gs = eslot + (size_t)blockIdx.x * SLOTSZ;
        for (int i = t; i < SLOTSZ; i += 1024) gs[i] = ssum[i];
    } else {
        // ----- node range-sum: one block per graph; binary-search boundaries -----
        const int g = blockIdx.x - EDGE_BLKS;
        __shared__ int sb[2];
        if (t < 2) {                         // lower_bound(batch, g + t)
            const int target = g + t;
            int lo = 0, hi = N_NODES;
            while (lo < hi) {
                const int mid = (lo + hi) >> 1;
                if (batch[mid] < target) lo = mid + 1; else hi = mid;
            }
            sb[t] = lo;
        }
        __syncthreads();
        const int s0 = sb[0], e0 = sb[1];

        const int dp = t & 63;               // float2 dim-pair: dims 2dp, 2dp+1
        const int off = t >> 6;              // row offset 0..15
        float ax0 = 0.f, ay0 = 0.f, ax1 = 0.f, ay1 = 0.f;
        float ax2 = 0.f, ay2 = 0.f, ax3 = 0.f, ay3 = 0.f;
        int r = s0 + off;
        for (; r + 48 < e0; r += 64) {
            const float2 v0 = *reinterpret_cast<const float2*>(x + (size_t)(r     ) * NODE_DIM + dp * 2);
            const float2 v1 = *reinterpret_cast<const float2*>(x + (size_t)(r + 16) * NODE_DIM + dp * 2);
            const float2 v2 = *reinterpret_cast<const float2*>(x + (size_t)(r + 32) * NODE_DIM + dp * 2);
            const float2 v3 = *reinterpret_cast<const float2*>(x + (size_t)(r + 48) * NODE_DIM + dp * 2);
            ax0 += v0.x; ay0 += v0.y; ax1 += v1.x; ay1 += v1.y;
            ax2 += v2.x; ay2 += v2.y; ax3 += v3.x; ay3 += v3.y;
        }
        for (; r < e0; r += 16) {
            const float2 v = *reinterpret_cast<const float2*>(x + (size_t)r * NODE_DIM + dp * 2);
            ax0 += v.x; ay0 += v.y;
        }

        float2* part2 = reinterpret_cast<float2*>(ssum);   // 8 KB of ssum
        part2[t] = float2{(ax0 + ax1) + (ax2 + ax3), (ay0 + ay1) + (ay2 + ay3)};
        __syncthreads();
        if (t < 64) {
            float sx = 0.f, sy = 0.f;
#pragma unroll 16
            for (int k = 0; k < 16; ++k) {
                const float2 v = part2[t + 64 * k];
                sx += v.x; sy += v.y;
            }
            reinterpret_cast<float2*>(nsum)[(size_t)g * 64 + t] = float2{sx, sy};
        }
        if (t == 0) ncnt[g] = fmaxf((float)(e0 - s0), 1.f);
    }
}

// ---------------- finalize + MLP fused: GPB graphs per block ---------------
__global__ __launch_bounds__(256) void finalize_mlp(const float* __restrict__ nsum,
                                                    const float* __restrict__ ncnt,
                                                    const int* __restrict__ eslot,
                                                    const float* __restrict__ u,
                                                    const float* __restrict__ W1, const float* __restrict__ b1,
                                                    const float* __restrict__ W2, const float* __restrict__ b2,
                                                    const float* __restrict__ W3, const float* __restrict__ b3,
                                                    float* __restrict__ out) {
    const int g0 = blockIdx.x * GPB;
    const int t = threadIdx.x;
    __shared__ float fs[GPB * IN_DIM];
    __shared__ long long redll[256];
    __shared__ long long redcnt[8];
    __shared__ float h[GPB][HIDDEN_DIM];
    __shared__ float h2[GPB][HIDDEN_DIM];
    __shared__ float red[GPB][256];
    __shared__ float s_ecnt[GPB];

    // edge dim partials: col = t&63 (g = col>>5, d = col&31), part = t>>6 over 4x64 slots
    {
        const int col = t & 63, part = t >> 6;
        const int g = col >> 5, d = col & 31;
        long long s = 0;
#pragma unroll 8
        for (int sl = part * 64; sl < part * 64 + 64; ++sl)
            s += eslot[(size_t)sl * SLOTSZ + (size_t)(g0 + g) * ROW33 + d];
        redll[t] = s;
    }
    if (t < 8) {    // counts: g = t&1, part = t>>1 over 4x64 slots
        const int g = t & 1, part = t >> 1;
        long long c = 0;
#pragma unroll 8
        for (int sl = part * 64; sl < part * 64 + 64; ++sl)
            c += eslot[(size_t)sl * SLOTSZ + (size_t)(g0 + g) * ROW33 + 32];
        redcnt[t] = c;
    }
    __syncthreads();
    if (t < GPB)
        s_ecnt[t] = fmaxf((float)(redcnt[t] + redcnt[t + 2] + redcnt[t + 4] + redcnt[t + 6]), 1.f);

    {   // node means: 2 graphs x 128 dims = 256 -> one per thread
        const int g = t >> 7, d = t & 127;
        fs[g * IN_DIM + d] = nsum[(size_t)(g0 + g) * NODE_DIM + d] / ncnt[g0 + g];
    }
    __syncthreads();
    if (t < 64) {   // edge means: combine 4 partials
        const long long tot = redll[t] + redll[t + 64] + redll[t + 128] + redll[t + 192];
        const int g = t >> 5, d = t & 31;
        fs[g * IN_DIM + NODE_DIM + d] = ((float)tot * FXINV) / s_ecnt[g];
    } else if (t < 192) {  // u copy: 2 graphs x 64
        const int i = t - 64, g = i >> 6, c = i & 63;
        fs[g * IN_DIM + NODE_DIM + EDGE_DIM + c] = u[(size_t)(g0 + g) * GLOBAL_DIM + c];
    }
    __syncthreads();

    // ---- MLP ----
    float acc0, acc1;
    const float bb1 = b1[t];
    acc0 = acc1 = bb1;
    for (int k = 0; k < IN_DIM; ++k) {
        const float w = W1[k * HIDDEN_DIM + t];
        acc0 = fmaf(fs[k], w, acc0);
        acc1 = fmaf(fs[IN_DIM + k], w, acc1);
    }
    h[0][t] = fmaxf(acc0, 0.f); h[1][t] = fmaxf(acc1, 0.f);
    __syncthreads();

    const float bb2 = b2[t];
    acc0 = acc1 = bb2;
    for (int k = 0; k < HIDDEN_DIM; ++k) {
        const float w = W2[k * HIDDEN_DIM + t];
        acc0 = fmaf(h[0][k], w, acc0);
        acc1 = fmaf(h[1][k], w, acc1);
    }
    h2[0][t] = fmaxf(acc0, 0.f); h2[1][t] = fmaxf(acc1, 0.f);
    __syncthreads();

    const int c3 = t & 63, q = t >> 6;
    acc0 = acc1 = 0.f;
    for (int k = q * 64; k < q * 64 + 64; ++k) {
        const float w = W3[k * GLOBAL_DIM + c3];
        acc0 = fmaf(h2[0][k], w, acc0);
        acc1 = fmaf(h2[1][k], w, acc1);
    }
    red[0][t] = acc0; red[1][t] = acc1;
    __syncthreads();
    if (t < GPB * GLOBAL_DIM) {
        const int g = t >> 6, c = t & 63;
        out[(size_t)(g0 + g) * GLOBAL_DIM + c] = red[g][c] + red[g][c + 64] +
                                                 red[g][c + 128] + red[g][c + 192] + b3[c];
    }
}

extern "C" void kernel_launch(void* const* d_in, const int* in_sizes, int n_in,
                              void* d_out, int out_size, void* d_ws, size_t ws_size,
                              hipStream_t stream) {
    const float* x         = (const float*)d_in[0];
    const int*   edge_idx  = (const int*)d_in[1];    // [2, E]; first E = sources
    const float* edge_attr = (const float*)d_in[2];
    const float* u         = (const float*)d_in[3];
    const int*   batch     = (const int*)d_in[4];
    const float* W1 = (const float*)d_in[5];
    const float* b1 = (const float*)d_in[6];
    const float* W2 = (const float*)d_in[7];
    const float* b2 = (const float*)d_in[8];
    const float* W3 = (const float*)d_in[9];
    const float* b3 = (const float*)d_in[10];
    float* out = (float*)d_out;

    int* ws32 = (int*)d_ws;
    float* nsum  = (float*)(ws32 + WS_NSUM);
    float* ncnt  = (float*)(ws32 + WS_NCNT);
    int*   eslot = ws32 + WS_ESLOT;

    bulk<<<EDGE_BLKS + N_GRAPHS, 1024, 0, stream>>>(edge_attr, edge_idx, x, batch,
                                                    eslot, nsum, ncnt);
    finalize_mlp<<<N_GRAPHS / GPB, 256, 0, stream>>>(nsum, ncnt, eslot, u,
                                                     W1, b1, W2, b2, W3, b3, out);
}